// Round 2
// baseline (1126.235 us; speedup 1.0000x reference)
//
#include <hip/hip_runtime.h>
#include <math.h>

// Problem constants: B=1024, E=64, N=32, D=64
#define NB 1024
#define NE 64
#define NN 32
#define ND 64
#define PAIRS (NB * NE)

// One WAVE (64 lanes) per (b,e) pair. No __syncthreads anywhere.
// Tile ownership: lane ln owns float4 index i*64+ln of the 32x64 tile
// (i=0..7)  ->  row n = 4*i + g (g = ln>>4), float4-col c = ln&15.
// All loads per instruction are 1KB contiguous per wave (perfect coalescing).
__global__ __launch_bounds__(256) void kgcn_wave_kernel(
    const float* __restrict__ self_v,   // [B,E,1,D]
    const float* __restrict__ nbr_v,    // [B,E,N,D]
    const float* __restrict__ nbr_r,    // [B,E,N,D]
    const float* __restrict__ user,     // [B,D]
    const float* __restrict__ W,        // [D, 2D] row-major
    const float* __restrict__ bias,     // [D]
    float* __restrict__ out)            // [B,E,D]
{
    const int t    = threadIdx.x;
    const int wv   = t >> 6;            // wave 0..3
    const int ln   = t & 63;            // lane 0..63
    const int pair = blockIdx.x * 4 + wv;
    const int b    = pair >> 6;         // / NE

    const int g = ln >> 4;              // row-group 0..3
    const int c = ln & 15;              // float4 col 0..15

    __shared__ float4 s_x4[4][32];      // per-wave concat(self, agg): 128 floats

    const float4* rel4  = (const float4*)(nbr_r + (size_t)pair * (NN * ND));
    const float4* nv4   = (const float4*)(nbr_v + (size_t)pair * (NN * ND));
    const float4* self4 = (const float4*)(self_v + (size_t)pair * ND);
    const float4* user4 = (const float4*)(user + (size_t)b * ND);

    // stage self half of the concat vector early (16 lanes, 256B)
    if (ln < 16) s_x4[wv][ln] = self4[ln];

    float4 u4 = user4[c];               // user[b], cached (reused by 64 pairs)

    // ---- load rel tile + prefetch nbr tile (16 coalesced b128 loads) ----
    float4 ra[8], va[8];
    #pragma unroll
    for (int i = 0; i < 8; ++i) ra[i] = rel4[i * 64 + ln];
    #pragma unroll
    for (int i = 0; i < 8; ++i) va[i] = nv4[i * 64 + ln];

    // ---- scores: sc[i] = user . rel[4i+g], allreduced over 16-lane segment ----
    float sc[8];
    #pragma unroll
    for (int i = 0; i < 8; ++i)
        sc[i] = ra[i].x * u4.x + ra[i].y * u4.y + ra[i].z * u4.z + ra[i].w * u4.w;

    #pragma unroll
    for (int off = 1; off < 16; off <<= 1) {
        #pragma unroll
        for (int i = 0; i < 8; ++i)
            sc[i] += __shfl_xor(sc[i], off, 16);
    }
    // every lane now holds score[4i+g] for i=0..7

    // ---- softmax over all 32 rows (cross-group allreduce via xor 16,32) ----
    float m = sc[0];
    #pragma unroll
    for (int i = 1; i < 8; ++i) m = fmaxf(m, sc[i]);
    m = fmaxf(m, __shfl_xor(m, 16, 64));
    m = fmaxf(m, __shfl_xor(m, 32, 64));

    float e[8], s = 0.f;
    #pragma unroll
    for (int i = 0; i < 8; ++i) { e[i] = __expf(sc[i] - m); s += e[i]; }
    s += __shfl_xor(s, 16, 64);
    s += __shfl_xor(s, 32, 64);
    const float inv = 1.f / s;

    // ---- agg[c] = sum_n p[n] * nbr[n][c] ----
    float4 acc = {0.f, 0.f, 0.f, 0.f};
    #pragma unroll
    for (int i = 0; i < 8; ++i) {
        const float p = e[i] * inv;
        acc.x = fmaf(p, va[i].x, acc.x);
        acc.y = fmaf(p, va[i].y, acc.y);
        acc.z = fmaf(p, va[i].z, acc.z);
        acc.w = fmaf(p, va[i].w, acc.w);
    }
    // combine the 4 row-groups (allreduce; lanes 0..15 hold final agg col c)
    acc.x += __shfl_xor(acc.x, 16, 64); acc.x += __shfl_xor(acc.x, 32, 64);
    acc.y += __shfl_xor(acc.y, 16, 64); acc.y += __shfl_xor(acc.y, 32, 64);
    acc.z += __shfl_xor(acc.z, 16, 64); acc.z += __shfl_xor(acc.z, 32, 64);
    acc.w += __shfl_xor(acc.w, 16, 64); acc.w += __shfl_xor(acc.w, 32, 64);

    if (ln < 16) s_x4[wv][16 + ln] = acc;   // agg half of concat
    __builtin_amdgcn_wave_barrier();        // in-wave LDS ordering (no HW cost)

    // ---- out[dout] = relu(x . W[dout] + b[dout]), dout = ln ----
    float accO = bias[ln];
    const float4* Wr = (const float4*)W + ln * 32;   // W row: 32 float4
    #pragma unroll
    for (int k = 0; k < 32; ++k) {
        float4 w = Wr[k];                 // L1-resident (W = 32KB exactly)
        float4 x = s_x4[wv][k];           // LDS broadcast, conflict-free
        accO = fmaf(w.x, x.x, fmaf(w.y, x.y, fmaf(w.z, x.z, fmaf(w.w, x.w, accO))));
    }
    out[(size_t)pair * ND + ln] = fmaxf(accO, 0.f);  // 256B contiguous per wave
}

extern "C" void kernel_launch(void* const* d_in, const int* in_sizes, int n_in,
                              void* d_out, int out_size, void* d_ws, size_t ws_size,
                              hipStream_t stream) {
    const float* self_v = (const float*)d_in[0];
    const float* nbr_v  = (const float*)d_in[1];
    const float* nbr_r  = (const float*)d_in[2];
    const float* user   = (const float*)d_in[3];
    const float* W      = (const float*)d_in[4];
    const float* bias   = (const float*)d_in[5];
    float* out          = (float*)d_out;

    kgcn_wave_kernel<<<PAIRS / 4, 256, 0, stream>>>(
        self_v, nbr_v, nbr_r, user, W, bias, out);
}